// Round 2
// baseline (1413.068 us; speedup 1.0000x reference)
//
#include <hip/hip_runtime.h>
#include <math.h>

#define G_NUM 1024
#define H 128
#define NNODES 100000
#define NEDGES 500000
#define EPS_LN 1e-5f

typedef __attribute__((ext_vector_type(8))) short short8;
typedef __attribute__((ext_vector_type(4))) float f32x4;

__device__ __forceinline__ float gelu_exact(float x) {
    return 0.5f * x * (1.0f + erff(x * 0.70710678118654752440f));
}
__device__ __forceinline__ unsigned short f2bf(float x) {
    unsigned u = __float_as_uint(x);
    return (unsigned short)((u + 0x7FFFu + ((u >> 16) & 1u)) >> 16);
}

// ---- K0: probe selected_mask storage dtype ----------------------------------
__global__ void k_probe_mask(const unsigned* __restrict__ mw, int* __restrict__ flag) {
    unsigned v = mw[threadIdx.x];
    if (v == 0x3F800000u) atomicOr(flag, 2);
    else if (v > 1u) atomicOr(flag, 1);
}

// ---- K_prep: W1' = diag(blng)*bw1, bf16, B-fragment order -------------------
// dst: ((s*8 + t8)*64 + lane)*8 + j ; s=k>>5, quad=(k&31)>>3, j=k&7,
// lane=quad*16+(n&15), t8=n>>4
__global__ void k_prep(const float* __restrict__ bw1, const float* __restrict__ blng,
                       unsigned short* __restrict__ bwbf) {
    int e = blockIdx.x * 256 + threadIdx.x;
    if (e >= 384 * 128) return;
    int k = e >> 7, n = e & 127;
    int s = k >> 5, krel = k & 31;
    int quad = krel >> 3, j = krel & 7;
    int lane = quad * 16 + (n & 15);
    int t8 = n >> 4;
    bwbf[((s * 8 + t8) * 64 + lane) * 8 + j] = f2bf(bw1[e] * blng[k]);
}

// ---- K_prep2: colsum[n] = sum_k blng[k]*bw1[k][n]; bb1p[n] = bb1[n]+sum_k blnb[k]*bw1[k][n]
__global__ __launch_bounds__(128) void k_prep2(const float* __restrict__ bw1,
                                               const float* __restrict__ blng,
                                               const float* __restrict__ blnb,
                                               const float* __restrict__ bb1,
                                               float* __restrict__ colsum,
                                               float* __restrict__ bb1p) {
    int n = threadIdx.x;
    float cs = 0.f, bs = 0.f;
    for (int k = 0; k < 384; ++k) {
        float w = bw1[k * H + n];
        cs += blng[k] * w;
        bs += blnb[k] * w;
    }
    colsum[n] = cs;
    bb1p[n] = bb1[n] + bs;
}

// ---- K1: fused aggregate_start + context MLP + log_z -> out[:,0] ------------
__global__ __launch_bounds__(128) void k_graph(
    const float* __restrict__ node_tokens, const float* __restrict__ question,
    const int* __restrict__ locals_, const int* __restrict__ ptr,
    const float* __restrict__ cw1, const float* __restrict__ cb1,
    const float* __restrict__ cw2, const float* __restrict__ cb2,
    const float* __restrict__ ln1g, const float* __restrict__ ln1b,
    const float* __restrict__ zw1, const float* __restrict__ zb1,
    const float* __restrict__ zw2, const float* __restrict__ zb2,
    float* __restrict__ out)
{
    int g = blockIdx.x, t = threadIdx.x;
    __shared__ float xin[2 * H];
    __shared__ float buf[H];
    __shared__ float r1[2], r2[2];
    __shared__ float sc[16];
    // --- aggregate_start ---
    int p0 = ptr[g], p1 = ptr[g + 1];
    int cnt = p1 - p0; if (cnt > 16) cnt = 16;
    float q = question[(size_t)g * H + t];
    xin[H + t] = q;
    for (int s = 0; s < cnt; ++s) {
        int node = locals_[p0 + s];
        float v = node_tokens[(size_t)node * H + t] * q;
        for (int off = 32; off; off >>= 1) v += __shfl_down(v, off);
        if ((t & 63) == 0) r1[t >> 6] = v;
        __syncthreads();
        if (t == 0) sc[s] = (r1[0] + r1[1]) * 0.08838834764831845f;
        __syncthreads();
    }
    float m = -1e30f;
    for (int s = 0; s < cnt; ++s) m = fmaxf(m, sc[s]);
    float den = 0.f;
    for (int s = 0; s < cnt; ++s) den += expf(sc[s] - m);
    float acc0 = 0.f;
    for (int s = 0; s < cnt; ++s) {
        float a = expf(sc[s] - m) / den;
        acc0 += a * node_tokens[(size_t)locals_[p0 + s] * H + t];
    }
    xin[t] = acc0;
    __syncthreads();
    // --- ctx MLP ---
    float a1 = cb1[t];
    for (int k = 0; k < 2 * H; ++k) a1 += xin[k] * cw1[k * H + t];
    buf[t] = gelu_exact(a1);
    __syncthreads();
    float ctx = cb2[t];
    for (int k = 0; k < H; ++k) ctx += buf[k] * cw2[k * H + t];
    // --- LN + z head ---
    float s1 = ctx, s2 = ctx * ctx;
    for (int off = 32; off; off >>= 1) { s1 += __shfl_down(s1, off); s2 += __shfl_down(s2, off); }
    if ((t & 63) == 0) { r1[t >> 6] = s1; r2[t >> 6] = s2; }
    __syncthreads();
    float mean = (r1[0] + r1[1]) * (1.f / H);
    float var  = (r2[0] + r2[1]) * (1.f / H) - mean * mean;
    float xn = (ctx - mean) * rsqrtf(var + EPS_LN) * ln1g[t] + ln1b[t];
    __syncthreads();
    buf[t] = xn;
    __syncthreads();
    float a2 = zb1[t];
    for (int k = 0; k < H; ++k) a2 += buf[k] * zw1[k * H + t];
    float p = gelu_exact(a2) * zw2[t];
    for (int off = 32; off; off >>= 1) p += __shfl_down(p, off);
    if ((t & 63) == 0) r1[t >> 6] = p;
    __syncthreads();
    if (t == 0) out[(size_t)g * 3 + 0] = r1[0] + r1[1] + zb2[0];
}

// ---- K4: persistent edge MLP via MFMA, full B matrix resident in LDS --------
// 256 blocks x 1024 threads (16 waves), 1 block/CU (LDS-bound). Stage all
// 96 KB of bf16 weights into LDS ONCE, then grid-stride over 256-edge tiles
// with NO barriers. Round-1 lesson: launch_bounds(1024,4) let the compiler
// allocate 64 VGPRs chasing 8 waves/EU (impossible here: LDS caps at 4) and
// the acc+frag set spilled to scratch (WRITE_SIZE 18->420 MB). Fix:
// waves_per_eu(4,4) pins the budget at 128 VGPRs, and the k-chunk loop is
// fused (one frag live, not 12) with epilogue constants de-hoisted.
__global__ __attribute__((amdgpu_flat_work_group_size(1024, 1024)))
           __attribute__((amdgpu_waves_per_eu(4, 4)))
void k_edges(
    const float* __restrict__ node_tokens, const float* __restrict__ question,
    const float* __restrict__ edge_tokens, const int* __restrict__ edge_batch,
    const int* __restrict__ edge_index,
    const unsigned short* __restrict__ bwbf, const float* __restrict__ colsum,
    const float* __restrict__ bb1p, const float* __restrict__ bw2,
    const float* __restrict__ bb2, float* __restrict__ logits,
    float* __restrict__ sumexp)
{
    __shared__ unsigned short bwlds[49152];   // 96 KB: full 384x128 bf16 W1'
    int t = threadIdx.x, lane = t & 63, w = t >> 6;
    int quad = lane >> 4, n16 = lane & 15;

    // one-time stage of the whole weight matrix: 6144 uint4 = 96 KB
    {
        const uint4* src = (const uint4*)bwbf;
        uint4* dst = (uint4*)bwlds;
        #pragma unroll
        for (int i = 0; i < 6; ++i) dst[t + i * 1024] = src[t + i * 1024];
    }
    const int* tgt_idx = edge_index + NEDGES;
    float bb2v = bb2[0];
    __syncthreads();   // the ONLY barrier

    const int NTILES = (NEDGES + 255) / 256;
    for (int tile = blockIdx.x; tile < NTILES; tile += gridDim.x) {
        int e0w = tile * 256 + w * 16;
        int e = e0w + n16;
        int ec = e < NEDGES ? e : NEDGES - 1;
        int qrow = edge_batch[ec];
        int trow = tgt_idx[ec];
        const float4* ep  = (const float4*)(edge_tokens + (size_t)ec * H);
        const float4* qp  = (const float4*)(question + (size_t)qrow * H);
        const float4* np_ = (const float4*)(node_tokens + (size_t)trow * H);

        float s1 = 0.f, s2 = 0.f;
        f32x4 acc[8];
        #pragma unroll
        for (int q = 0; q < 8; ++q) acc[q] = (f32x4){0.f, 0.f, 0.f, 0.f};

        // fused: load one 32-wide k-chunk fragment, immediately feed 8 MFMAs.
        // LN stats (mu/inv) are applied only in the epilogue, so they never
        // gate the MFMA chain. Only ONE frag live at a time (8 VGPRs).
        #pragma unroll
        for (int s = 0; s < 12; ++s) {
            int c0 = s * 8 + quad * 2;          // float4 index 0..95 of the 3H row
            const float4* base = (s < 4) ? ep : (s < 8) ? qp : np_;
            int cc = c0 - ((s < 4) ? 0 : (s < 8) ? 32 : 64);
            float4 v0 = base[cc], v1 = base[cc + 1];
            s1 += v0.x + v0.y + v0.z + v0.w + v1.x + v1.y + v1.z + v1.w;
            s2 += v0.x*v0.x + v0.y*v0.y + v0.z*v0.z + v0.w*v0.w
                + v1.x*v1.x + v1.y*v1.y + v1.z*v1.z + v1.w*v1.w;
            short8 f;
            f[0] = (short)f2bf(v0.x); f[1] = (short)f2bf(v0.y);
            f[2] = (short)f2bf(v0.z); f[3] = (short)f2bf(v0.w);
            f[4] = (short)f2bf(v1.x); f[5] = (short)f2bf(v1.y);
            f[6] = (short)f2bf(v1.z); f[7] = (short)f2bf(v1.w);
            #pragma unroll
            for (int t8 = 0; t8 < 8; ++t8) {
                short8 b = *(const short8*)&bwlds[((s * 8 + t8) * 64 + lane) * 8];
                acc[t8] = __builtin_amdgcn_mfma_f32_16x16x32_bf16(f, b, acc[t8], 0, 0, 0);
            }
        }

        // full-row LN stats: reduce across the 4 quads sharing this edge row
        s1 += __shfl_xor(s1, 16); s1 += __shfl_xor(s1, 32);
        s2 += __shfl_xor(s2, 16); s2 += __shfl_xor(s2, 32);
        float mu  = s1 * (1.f / 384.f);
        float inv = rsqrtf(s2 * (1.f / 384.f) - mu * mu + EPS_LN);

        // epilogue: y = (acc - mu*colsum)*inv + bb1p ; logit = sum gelu(y)*bw2 + bb2
        // constants loaded here (L1-hot), not hoisted across the main loop
        #pragma unroll
        for (int r = 0; r < 4; ++r) {
            float mu_r  = __shfl(mu,  quad * 4 + r);
            float inv_r = __shfl(inv, quad * 4 + r);
            float ssum = 0.f;
            #pragma unroll
            for (int t8 = 0; t8 < 8; ++t8) {
                int n = t8 * 16 + n16;
                float y = (acc[t8][r] - mu_r * colsum[n]) * inv_r + bb1p[n];
                ssum += gelu_exact(y) * bw2[n];
            }
            ssum += __shfl_xor(ssum, 1);
            ssum += __shfl_xor(ssum, 2);
            ssum += __shfl_xor(ssum, 4);
            ssum += __shfl_xor(ssum, 8);
            if (n16 == 0) {
                int ei = e0w + quad * 4 + r;
                if (ei < NEDGES) {
                    float lg = ssum + bb2v;
                    logits[ei] = lg;
                    // logits are O(1): exp-sum without max-shift is safe
                    atomicAdd(&sumexp[tgt_idx[ei]], expf(lg));
                }
            }
        }
    }
}

// ---- K6: masked per-graph sum of log-probs (LDS slot aggregation) -----------
__global__ __launch_bounds__(256) void k_logpb(
    const float* __restrict__ logits,
    const int* __restrict__ edge_index,
    const int* __restrict__ edge_batch,
    const void* __restrict__ mask,
    const int* __restrict__ flag,
    const float* __restrict__ sumexp,
    float* __restrict__ logpb, int* __restrict__ selcnt)
{
    __shared__ float lacc[8];
    __shared__ int lcnt[8];
    __shared__ int g0s, big;
    int t = threadIdx.x;
    int e0 = blockIdx.x * 256;
    if (t == 0) {
        int ga = edge_batch[e0 < NEDGES ? e0 : NEDGES - 1];
        int el = e0 + 255; if (el >= NEDGES) el = NEDGES - 1;
        int gb = edge_batch[el];
        g0s = ga; big = (gb - ga > 7);
    }
    if (t < 8) { lacc[t] = 0.f; lcnt[t] = 0; }
    __syncthreads();
    int e = e0 + t;
    if (e < NEDGES) {
        int mode = *flag;
        bool sel;
        if (mode & 2)      sel = ((const float*)mask)[e] != 0.f;
        else if (mode & 1) sel = ((const unsigned char*)mask)[e] != 0;
        else               sel = ((const int*)mask)[e] != 0;
        if (sel) {
            int tg = edge_index[NEDGES + e];
            float lp = logits[e] - logf(sumexp[tg]);
            int g = edge_batch[e];
            if (!big) {
                atomicAdd(&lacc[g - g0s], lp);
                atomicAdd(&lcnt[g - g0s], 1);
            } else {
                atomicAdd(&logpb[g], lp);
                atomicAdd(&selcnt[g], 1);
            }
        }
    }
    __syncthreads();
    if (t < 8 && !big && lcnt[t] > 0) {
        atomicAdd(&logpb[g0s + t], lacc[t]);
        atomicAdd(&selcnt[g0s + t], lcnt[t]);
    }
}

// ---- K7: finalize out[:,1] and out[:,2] -------------------------------------
__global__ __launch_bounds__(1024) void k_final(const float* __restrict__ logpb,
                                                const int* __restrict__ selcnt,
                                                float* __restrict__ out)
{
    int g = threadIdx.x;
    float lpb = logpb[g];
    int has = selcnt[g] > 0;
    float s = has ? -lpb : 0.f;
    int c = has;
    __shared__ float rn[16];
    __shared__ int rh[16];
    __shared__ float pbnll_s;
    for (int off = 32; off; off >>= 1) { s += __shfl_down(s, off); c += __shfl_down(c, off); }
    if ((g & 63) == 0) { rn[g >> 6] = s; rh[g >> 6] = c; }
    __syncthreads();
    if (g == 0) {
        float ts = 0.f; int tc = 0;
        for (int i = 0; i < 16; ++i) { ts += rn[i]; tc += rh[i]; }
        pbnll_s = ts / (float)(tc > 0 ? tc : 1);
    }
    __syncthreads();
    out[(size_t)g * 3 + 1] = lpb;
    out[(size_t)g * 3 + 2] = pbnll_s;
}

extern "C" void kernel_launch(void* const* d_in, const int* in_sizes, int n_in,
                              void* d_out, int out_size, void* d_ws, size_t ws_size,
                              hipStream_t stream) {
    const float* node_tokens = (const float*)d_in[0];
    const float* question    = (const float*)d_in[1];
    const float* edge_tokens = (const float*)d_in[2];
    const int*   locals_     = (const int*)d_in[3];
    const int*   ptr         = (const int*)d_in[4];
    const int*   edge_batch  = (const int*)d_in[5];
    const void*  mask        = d_in[6];
    const int*   edge_index  = (const int*)d_in[7];
    const float* ln1g = (const float*)d_in[8];
    const float* ln1b = (const float*)d_in[9];
    const float* zw1  = (const float*)d_in[10];
    const float* zb1  = (const float*)d_in[11];
    const float* zw2  = (const float*)d_in[12];
    const float* zb2  = (const float*)d_in[13];
    const float* cw1  = (const float*)d_in[14];
    const float* cb1  = (const float*)d_in[15];
    const float* cw2  = (const float*)d_in[16];
    const float* cb2  = (const float*)d_in[17];
    const float* blng = (const float*)d_in[18];
    const float* blnb = (const float*)d_in[19];
    const float* bw1  = (const float*)d_in[20];
    const float* bb1  = (const float*)d_in[21];
    const float* bw2  = (const float*)d_in[22];
    const float* bb2  = (const float*)d_in[23];
    float* out = (float*)d_out;

    // workspace layout (float units)
    float* ws = (float*)d_ws;
    float* sumexp  = ws;                                // 100000 (zeroed)
    float* logpb   = ws + 100000;                       // 1024  (zeroed)
    int*   selcnt  = (int*)(ws + 101024);               // 1024  (zeroed)
    int*   flag    = (int*)(ws + 102048);               // 1     (zeroed)
    float* logits  = ws + 102052;                       // 500000
    float* colsum  = ws + 602052;                       // 128
    float* bb1p    = ws + 602180;                       // 128
    unsigned short* bwbf = (unsigned short*)(ws + 602308); // 49152 bf16 (16B-aligned)

    hipMemsetAsync(d_ws, 0, (size_t)102049 * 4, stream);
    k_probe_mask<<<1, 256, 0, stream>>>((const unsigned*)mask, flag);
    k_prep<<<192, 256, 0, stream>>>(bw1, blng, bwbf);
    k_prep2<<<1, 128, 0, stream>>>(bw1, blng, blnb, bb1, colsum, bb1p);
    k_graph<<<G_NUM, 128, 0, stream>>>(node_tokens, question, locals_, ptr,
                                       cw1, cb1, cw2, cb2, ln1g, ln1b,
                                       zw1, zb1, zw2, zb2, out);
    k_edges<<<256, 1024, 0, stream>>>(node_tokens, question, edge_tokens,
                                      edge_batch, edge_index, bwbf,
                                      colsum, bb1p, bw2, bb2,
                                      logits, sumexp);
    int eb = (NEDGES + 255) / 256;
    k_logpb<<<eb, 256, 0, stream>>>(logits, edge_index, edge_batch, mask, flag,
                                    sumexp, logpb, selcnt);
    k_final<<<1, 1024, 0, stream>>>(logpb, selcnt, out);
}

// Round 3
// 730.562 us; speedup vs baseline: 1.9342x; 1.9342x over previous
//
#include <hip/hip_runtime.h>
#include <math.h>

#define G_NUM 1024
#define H 128
#define NNODES 100000
#define NEDGES 500000
#define EPS_LN 1e-5f

typedef __attribute__((ext_vector_type(8))) short short8;
typedef __attribute__((ext_vector_type(4))) float f32x4;

__device__ __forceinline__ float gelu_exact(float x) {
    return 0.5f * x * (1.0f + erff(x * 0.70710678118654752440f));
}
__device__ __forceinline__ unsigned short f2bf(float x) {
    unsigned u = __float_as_uint(x);
    return (unsigned short)((u + 0x7FFFu + ((u >> 16) & 1u)) >> 16);
}

// ---- K0: probe selected_mask storage dtype ----------------------------------
__global__ void k_probe_mask(const unsigned* __restrict__ mw, int* __restrict__ flag) {
    unsigned v = mw[threadIdx.x];
    if (v == 0x3F800000u) atomicOr(flag, 2);
    else if (v > 1u) atomicOr(flag, 1);
}

// ---- K_prep: W1' = diag(blng)*bw1, bf16, B-fragment order -------------------
// dst: ((s*8 + t8)*64 + lane)*8 + j ; s=k>>5, quad=(k&31)>>3, j=k&7,
// lane=quad*16+(n&15), t8=n>>4
__global__ void k_prep(const float* __restrict__ bw1, const float* __restrict__ blng,
                       unsigned short* __restrict__ bwbf) {
    int e = blockIdx.x * 256 + threadIdx.x;
    if (e >= 384 * 128) return;
    int k = e >> 7, n = e & 127;
    int s = k >> 5, krel = k & 31;
    int quad = krel >> 3, j = krel & 7;
    int lane = quad * 16 + (n & 15);
    int t8 = n >> 4;
    bwbf[((s * 8 + t8) * 64 + lane) * 8 + j] = f2bf(bw1[e] * blng[k]);
}

// ---- K_prep2: colsum[n] = sum_k blng[k]*bw1[k][n]; bb1p[n] = bb1[n]+sum_k blnb[k]*bw1[k][n]
__global__ __launch_bounds__(128) void k_prep2(const float* __restrict__ bw1,
                                               const float* __restrict__ blng,
                                               const float* __restrict__ blnb,
                                               const float* __restrict__ bb1,
                                               float* __restrict__ colsum,
                                               float* __restrict__ bb1p) {
    int n = threadIdx.x;
    float cs = 0.f, bs = 0.f;
    for (int k = 0; k < 384; ++k) {
        float w = bw1[k * H + n];
        cs += blng[k] * w;
        bs += blnb[k] * w;
    }
    colsum[n] = cs;
    bb1p[n] = bb1[n] + bs;
}

// ---- K1: fused aggregate_start + context MLP + log_z -> out[:,0] ------------
__global__ __launch_bounds__(128) void k_graph(
    const float* __restrict__ node_tokens, const float* __restrict__ question,
    const int* __restrict__ locals_, const int* __restrict__ ptr,
    const float* __restrict__ cw1, const float* __restrict__ cb1,
    const float* __restrict__ cw2, const float* __restrict__ cb2,
    const float* __restrict__ ln1g, const float* __restrict__ ln1b,
    const float* __restrict__ zw1, const float* __restrict__ zb1,
    const float* __restrict__ zw2, const float* __restrict__ zb2,
    float* __restrict__ out)
{
    int g = blockIdx.x, t = threadIdx.x;
    __shared__ float xin[2 * H];
    __shared__ float buf[H];
    __shared__ float r1[2], r2[2];
    __shared__ float sc[16];
    // --- aggregate_start ---
    int p0 = ptr[g], p1 = ptr[g + 1];
    int cnt = p1 - p0; if (cnt > 16) cnt = 16;
    float q = question[(size_t)g * H + t];
    xin[H + t] = q;
    for (int s = 0; s < cnt; ++s) {
        int node = locals_[p0 + s];
        float v = node_tokens[(size_t)node * H + t] * q;
        for (int off = 32; off; off >>= 1) v += __shfl_down(v, off);
        if ((t & 63) == 0) r1[t >> 6] = v;
        __syncthreads();
        if (t == 0) sc[s] = (r1[0] + r1[1]) * 0.08838834764831845f;
        __syncthreads();
    }
    float m = -1e30f;
    for (int s = 0; s < cnt; ++s) m = fmaxf(m, sc[s]);
    float den = 0.f;
    for (int s = 0; s < cnt; ++s) den += expf(sc[s] - m);
    float acc0 = 0.f;
    for (int s = 0; s < cnt; ++s) {
        float a = expf(sc[s] - m) / den;
        acc0 += a * node_tokens[(size_t)locals_[p0 + s] * H + t];
    }
    xin[t] = acc0;
    __syncthreads();
    // --- ctx MLP ---
    float a1 = cb1[t];
    for (int k = 0; k < 2 * H; ++k) a1 += xin[k] * cw1[k * H + t];
    buf[t] = gelu_exact(a1);
    __syncthreads();
    float ctx = cb2[t];
    for (int k = 0; k < H; ++k) ctx += buf[k] * cw2[k * H + t];
    // --- LN + z head ---
    float s1 = ctx, s2 = ctx * ctx;
    for (int off = 32; off; off >>= 1) { s1 += __shfl_down(s1, off); s2 += __shfl_down(s2, off); }
    if ((t & 63) == 0) { r1[t >> 6] = s1; r2[t >> 6] = s2; }
    __syncthreads();
    float mean = (r1[0] + r1[1]) * (1.f / H);
    float var  = (r2[0] + r2[1]) * (1.f / H) - mean * mean;
    float xn = (ctx - mean) * rsqrtf(var + EPS_LN) * ln1g[t] + ln1b[t];
    __syncthreads();
    buf[t] = xn;
    __syncthreads();
    float a2 = zb1[t];
    for (int k = 0; k < H; ++k) a2 += buf[k] * zw1[k * H + t];
    float p = gelu_exact(a2) * zw2[t];
    for (int off = 32; off; off >>= 1) p += __shfl_down(p, off);
    if ((t & 63) == 0) r1[t >> 6] = p;
    __syncthreads();
    if (t == 0) out[(size_t)g * 3 + 0] = r1[0] + r1[1] + zb2[0];
}

// ---- K4: edge MLP via MFMA, B read straight from global (L2-hot), NO LDS ----
// 256 threads = 4 waves, each wave owns 32 edges (two 16-row A fragments
// sharing each B fragment -> halves B L2 traffic to 1.5 GB ~= 43 us at L2 BW).
// No __syncthreads anywhere; no LDS; occupancy bounded only by VGPRs.
// Round-1/2 lesson (in-code so it isn't re-tried): 1024-thread blocks make the
// allocator pin 64 VGPRs chasing 8 waves/EU and spill ~500 MB to scratch;
// amdgpu_waves_per_eu/launch_bounds mins do NOT override it. 256-thread
// blocks with bare __launch_bounds__(256) are the proven-good regime (r0: 96
// VGPR, zero spill).
__global__ __launch_bounds__(256) void k_edges(
    const float* __restrict__ node_tokens, const float* __restrict__ question,
    const float* __restrict__ edge_tokens, const int* __restrict__ edge_batch,
    const int* __restrict__ edge_index,
    const unsigned short* __restrict__ bwbf, const float* __restrict__ colsum,
    const float* __restrict__ bb1p, const float* __restrict__ bw2,
    const float* __restrict__ bb2, float* __restrict__ logits,
    float* __restrict__ sumexp)
{
    int t = threadIdx.x, lane = t & 63, w = t >> 6;
    int quad = lane >> 4, n16 = lane & 15;
    const int* tgt_idx = edge_index + NEDGES;

    int e0w = blockIdx.x * 128 + w * 32;      // this wave's 32 edges
    // half A: edges e0w + n16 ; half B: edges e0w + 16 + n16
    int ea = e0w + n16;       int eca = ea < NEDGES ? ea : NEDGES - 1;
    int eb = e0w + 16 + n16;  int ecb = eb < NEDGES ? eb : NEDGES - 1;
    int qra = edge_batch[eca], qrb = edge_batch[ecb];
    int tra = tgt_idx[eca],    trb = tgt_idx[ecb];
    const float4* epa = (const float4*)(edge_tokens + (size_t)eca * H);
    const float4* qpa = (const float4*)(question + (size_t)qra * H);
    const float4* npa = (const float4*)(node_tokens + (size_t)tra * H);
    const float4* epb = (const float4*)(edge_tokens + (size_t)ecb * H);
    const float4* qpb = (const float4*)(question + (size_t)qrb * H);
    const float4* npb = (const float4*)(node_tokens + (size_t)trb * H);

    float s1a = 0.f, s2a = 0.f, s1b = 0.f, s2b = 0.f;
    f32x4 acc0[8], acc1[8];
    #pragma unroll
    for (int i = 0; i < 8; ++i) { acc0[i] = (f32x4){0,0,0,0}; acc1[i] = (f32x4){0,0,0,0}; }

    #pragma unroll
    for (int s = 0; s < 12; ++s) {
        int c0 = s * 8 + quad * 2;            // float4 index 0..95 of the 3H row
        int cc = c0 - ((s < 4) ? 0 : (s < 8) ? 32 : 64);
        const float4* basea = (s < 4) ? epa : (s < 8) ? qpa : npa;
        const float4* baseb = (s < 4) ? epb : (s < 8) ? qpb : npb;
        float4 v0 = basea[cc], v1 = basea[cc + 1];
        float4 u0 = baseb[cc], u1 = baseb[cc + 1];
        s1a += v0.x + v0.y + v0.z + v0.w + v1.x + v1.y + v1.z + v1.w;
        s2a += v0.x*v0.x + v0.y*v0.y + v0.z*v0.z + v0.w*v0.w
             + v1.x*v1.x + v1.y*v1.y + v1.z*v1.z + v1.w*v1.w;
        s1b += u0.x + u0.y + u0.z + u0.w + u1.x + u1.y + u1.z + u1.w;
        s2b += u0.x*u0.x + u0.y*u0.y + u0.z*u0.z + u0.w*u0.w
             + u1.x*u1.x + u1.y*u1.y + u1.z*u1.z + u1.w*u1.w;
        short8 fa, fb;
        fa[0] = (short)f2bf(v0.x); fa[1] = (short)f2bf(v0.y);
        fa[2] = (short)f2bf(v0.z); fa[3] = (short)f2bf(v0.w);
        fa[4] = (short)f2bf(v1.x); fa[5] = (short)f2bf(v1.y);
        fa[6] = (short)f2bf(v1.z); fa[7] = (short)f2bf(v1.w);
        fb[0] = (short)f2bf(u0.x); fb[1] = (short)f2bf(u0.y);
        fb[2] = (short)f2bf(u0.z); fb[3] = (short)f2bf(u0.w);
        fb[4] = (short)f2bf(u1.x); fb[5] = (short)f2bf(u1.y);
        fb[6] = (short)f2bf(u1.z); fb[7] = (short)f2bf(u1.w);
        #pragma unroll
        for (int t8 = 0; t8 < 8; ++t8) {
            // coalesced 16 B/lane from global; 96 KB matrix is L2-resident
            short8 b = *(const short8*)&bwbf[((s * 8 + t8) * 64 + lane) * 8];
            acc0[t8] = __builtin_amdgcn_mfma_f32_16x16x32_bf16(fa, b, acc0[t8], 0, 0, 0);
            acc1[t8] = __builtin_amdgcn_mfma_f32_16x16x32_bf16(fb, b, acc1[t8], 0, 0, 0);
        }
    }

    // full-row LN stats: reduce across the 4 quads sharing each edge row
    s1a += __shfl_xor(s1a, 16); s1a += __shfl_xor(s1a, 32);
    s2a += __shfl_xor(s2a, 16); s2a += __shfl_xor(s2a, 32);
    s1b += __shfl_xor(s1b, 16); s1b += __shfl_xor(s1b, 32);
    s2b += __shfl_xor(s2b, 16); s2b += __shfl_xor(s2b, 32);
    float mua  = s1a * (1.f / 384.f);
    float inva = rsqrtf(s2a * (1.f / 384.f) - mua * mua + EPS_LN);
    float mub  = s1b * (1.f / 384.f);
    float invb = rsqrtf(s2b * (1.f / 384.f) - mub * mub + EPS_LN);
    float bb2v = bb2[0];

    // epilogue per half: y = (acc - mu*colsum)*inv + bb1p ; logit = sum gelu(y)*bw2 + bb2
    #pragma unroll
    for (int h = 0; h < 2; ++h) {
        float muh  = h ? mub : mua;
        float invh = h ? invb : inva;
        #pragma unroll
        for (int r = 0; r < 4; ++r) {
            float mu_r  = __shfl(muh,  quad * 4 + r);
            float inv_r = __shfl(invh, quad * 4 + r);
            float ssum = 0.f;
            #pragma unroll
            for (int t8 = 0; t8 < 8; ++t8) {
                int n = t8 * 16 + n16;
                float a = h ? acc1[t8][r] : acc0[t8][r];
                float y = (a - mu_r * colsum[n]) * inv_r + bb1p[n];
                ssum += gelu_exact(y) * bw2[n];
            }
            ssum += __shfl_xor(ssum, 1);
            ssum += __shfl_xor(ssum, 2);
            ssum += __shfl_xor(ssum, 4);
            ssum += __shfl_xor(ssum, 8);
            if (n16 == 0) {
                int ei = e0w + h * 16 + quad * 4 + r;
                if (ei < NEDGES) {
                    float lg = ssum + bb2v;
                    logits[ei] = lg;
                    // logits are O(1): exp-sum without max-shift is safe
                    atomicAdd(&sumexp[tgt_idx[ei]], expf(lg));
                }
            }
        }
    }
}

// ---- K6: masked per-graph sum of log-probs (LDS slot aggregation) -----------
__global__ __launch_bounds__(256) void k_logpb(
    const float* __restrict__ logits,
    const int* __restrict__ edge_index,
    const int* __restrict__ edge_batch,
    const void* __restrict__ mask,
    const int* __restrict__ flag,
    const float* __restrict__ sumexp,
    float* __restrict__ logpb, int* __restrict__ selcnt)
{
    __shared__ float lacc[8];
    __shared__ int lcnt[8];
    __shared__ int g0s, big;
    int t = threadIdx.x;
    int e0 = blockIdx.x * 256;
    if (t == 0) {
        int ga = edge_batch[e0 < NEDGES ? e0 : NEDGES - 1];
        int el = e0 + 255; if (el >= NEDGES) el = NEDGES - 1;
        int gb = edge_batch[el];
        g0s = ga; big = (gb - ga > 7);
    }
    if (t < 8) { lacc[t] = 0.f; lcnt[t] = 0; }
    __syncthreads();
    int e = e0 + t;
    if (e < NEDGES) {
        int mode = *flag;
        bool sel;
        if (mode & 2)      sel = ((const float*)mask)[e] != 0.f;
        else if (mode & 1) sel = ((const unsigned char*)mask)[e] != 0;
        else               sel = ((const int*)mask)[e] != 0;
        if (sel) {
            int tg = edge_index[NEDGES + e];
            float lp = logits[e] - logf(sumexp[tg]);
            int g = edge_batch[e];
            if (!big) {
                atomicAdd(&lacc[g - g0s], lp);
                atomicAdd(&lcnt[g - g0s], 1);
            } else {
                atomicAdd(&logpb[g], lp);
                atomicAdd(&selcnt[g], 1);
            }
        }
    }
    __syncthreads();
    if (t < 8 && !big && lcnt[t] > 0) {
        atomicAdd(&logpb[g0s + t], lacc[t]);
        atomicAdd(&selcnt[g0s + t], lcnt[t]);
    }
}

// ---- K7: finalize out[:,1] and out[:,2] -------------------------------------
__global__ __launch_bounds__(1024) void k_final(const float* __restrict__ logpb,
                                                const int* __restrict__ selcnt,
                                                float* __restrict__ out)
{
    int g = threadIdx.x;
    float lpb = logpb[g];
    int has = selcnt[g] > 0;
    float s = has ? -lpb : 0.f;
    int c = has;
    __shared__ float rn[16];
    __shared__ int rh[16];
    __shared__ float pbnll_s;
    for (int off = 32; off; off >>= 1) { s += __shfl_down(s, off); c += __shfl_down(c, off); }
    if ((g & 63) == 0) { rn[g >> 6] = s; rh[g >> 6] = c; }
    __syncthreads();
    if (g == 0) {
        float ts = 0.f; int tc = 0;
        for (int i = 0; i < 16; ++i) { ts += rn[i]; tc += rh[i]; }
        pbnll_s = ts / (float)(tc > 0 ? tc : 1);
    }
    __syncthreads();
    out[(size_t)g * 3 + 1] = lpb;
    out[(size_t)g * 3 + 2] = pbnll_s;
}

extern "C" void kernel_launch(void* const* d_in, const int* in_sizes, int n_in,
                              void* d_out, int out_size, void* d_ws, size_t ws_size,
                              hipStream_t stream) {
    const float* node_tokens = (const float*)d_in[0];
    const float* question    = (const float*)d_in[1];
    const float* edge_tokens = (const float*)d_in[2];
    const int*   locals_     = (const int*)d_in[3];
    const int*   ptr         = (const int*)d_in[4];
    const int*   edge_batch  = (const int*)d_in[5];
    const void*  mask        = d_in[6];
    const int*   edge_index  = (const int*)d_in[7];
    const float* ln1g = (const float*)d_in[8];
    const float* ln1b = (const float*)d_in[9];
    const float* zw1  = (const float*)d_in[10];
    const float* zb1  = (const float*)d_in[11];
    const float* zw2  = (const float*)d_in[12];
    const float* zb2  = (const float*)d_in[13];
    const float* cw1  = (const float*)d_in[14];
    const float* cb1  = (const float*)d_in[15];
    const float* cw2  = (const float*)d_in[16];
    const float* cb2  = (const float*)d_in[17];
    const float* blng = (const float*)d_in[18];
    const float* blnb = (const float*)d_in[19];
    const float* bw1  = (const float*)d_in[20];
    const float* bb1  = (const float*)d_in[21];
    const float* bw2  = (const float*)d_in[22];
    const float* bb2  = (const float*)d_in[23];
    float* out = (float*)d_out;

    // workspace layout (float units)
    float* ws = (float*)d_ws;
    float* sumexp  = ws;                                // 100000 (zeroed)
    float* logpb   = ws + 100000;                       // 1024  (zeroed)
    int*   selcnt  = (int*)(ws + 101024);               // 1024  (zeroed)
    int*   flag    = (int*)(ws + 102048);               // 1     (zeroed)
    float* logits  = ws + 102052;                       // 500000
    float* colsum  = ws + 602052;                       // 128
    float* bb1p    = ws + 602180;                       // 128
    unsigned short* bwbf = (unsigned short*)(ws + 602308); // 49152 bf16 (16B-aligned)

    hipMemsetAsync(d_ws, 0, (size_t)102049 * 4, stream);
    k_probe_mask<<<1, 256, 0, stream>>>((const unsigned*)mask, flag);
    k_prep<<<192, 256, 0, stream>>>(bw1, blng, bwbf);
    k_prep2<<<1, 128, 0, stream>>>(bw1, blng, blnb, bb1, colsum, bb1p);
    k_graph<<<G_NUM, 128, 0, stream>>>(node_tokens, question, locals_, ptr,
                                       cw1, cb1, cw2, cb2, ln1g, ln1b,
                                       zw1, zb1, zw2, zb2, out);
    k_edges<<<(NEDGES + 127) / 128, 256, 0, stream>>>(node_tokens, question, edge_tokens,
                                                      edge_batch, edge_index, bwbf,
                                                      colsum, bb1p, bw2, bb2,
                                                      logits, sumexp);
    int eb = (NEDGES + 255) / 256;
    k_logpb<<<eb, 256, 0, stream>>>(logits, edge_index, edge_batch, mask, flag,
                                    sumexp, logpb, selcnt);
    k_final<<<1, 1024, 0, stream>>>(logpb, selcnt, out);
}

// Round 4
// 697.606 us; speedup vs baseline: 2.0256x; 1.0472x over previous
//
#include <hip/hip_runtime.h>
#include <math.h>

#define G_NUM 1024
#define H 128
#define NNODES 100000
#define NEDGES 500000
#define EPS_LN 1e-5f

typedef __attribute__((ext_vector_type(8))) short short8;
typedef __attribute__((ext_vector_type(4))) float f32x4;

__device__ __forceinline__ float gelu_exact(float x) {
    return 0.5f * x * (1.0f + erff(x * 0.70710678118654752440f));
}
__device__ __forceinline__ unsigned short f2bf(float x) {
    unsigned u = __float_as_uint(x);
    return (unsigned short)((u + 0x7FFFu + ((u >> 16) & 1u)) >> 16);
}

// ---- K_prep_all: fused {bw1 repack, colsum/bb1p, mask probe} in one launch --
// blocks 0..191: W1' = diag(blng)*bw1 -> bf16 fragment order
//   dst: ((s*8 + t8)*64 + lane)*8 + j ; s=k>>5, quad=(k&31)>>3, j=k&7,
//   lane=quad*16+(n&15), t8=n>>4
// blocks 192..319: n = blk-192: colsum[n], bb1p[n] via 256-thread reduction
//   (was a single 128-thread block with a 384-deep serial load loop)
// block 320: probe selected_mask storage dtype
__global__ __launch_bounds__(256) void k_prep_all(
    const float* __restrict__ bw1, const float* __restrict__ blng,
    const float* __restrict__ blnb, const float* __restrict__ bb1,
    unsigned short* __restrict__ bwbf, float* __restrict__ colsum,
    float* __restrict__ bb1p,
    const unsigned* __restrict__ mw, int* __restrict__ flag)
{
    __shared__ float rc[4], rb[4];
    int b = blockIdx.x, t = threadIdx.x;
    if (b < 192) {
        int e = b * 256 + t;          // 192*256 == 384*128 exactly
        int k = e >> 7, n = e & 127;
        int s = k >> 5, krel = k & 31;
        int quad = krel >> 3, j = krel & 7;
        int lane = quad * 16 + (n & 15);
        int t8 = n >> 4;
        bwbf[((s * 8 + t8) * 64 + lane) * 8 + j] = f2bf(bw1[e] * blng[k]);
    } else if (b < 320) {
        int n = b - 192;
        float cs = 0.f, bs = 0.f;
        for (int k = t; k < 384; k += 256) {
            float w = bw1[k * H + n];
            cs += blng[k] * w;
            bs += blnb[k] * w;
        }
        for (int off = 32; off; off >>= 1) {
            cs += __shfl_down(cs, off);
            bs += __shfl_down(bs, off);
        }
        if ((t & 63) == 0) { rc[t >> 6] = cs; rb[t >> 6] = bs; }
        __syncthreads();
        if (t == 0) {
            colsum[n] = rc[0] + rc[1] + rc[2] + rc[3];
            bb1p[n]   = bb1[n] + rb[0] + rb[1] + rb[2] + rb[3];
        }
    } else {
        unsigned v = mw[t];
        if (v == 0x3F800000u) atomicOr(flag, 2);
        else if (v > 1u) atomicOr(flag, 1);
    }
}

// ---- K1: fused aggregate_start + context MLP + log_z -> out[:,0] ------------
__global__ __launch_bounds__(128) void k_graph(
    const float* __restrict__ node_tokens, const float* __restrict__ question,
    const int* __restrict__ locals_, const int* __restrict__ ptr,
    const float* __restrict__ cw1, const float* __restrict__ cb1,
    const float* __restrict__ cw2, const float* __restrict__ cb2,
    const float* __restrict__ ln1g, const float* __restrict__ ln1b,
    const float* __restrict__ zw1, const float* __restrict__ zb1,
    const float* __restrict__ zw2, const float* __restrict__ zb2,
    float* __restrict__ out)
{
    int g = blockIdx.x, t = threadIdx.x;
    __shared__ float xin[2 * H];
    __shared__ float buf[H];
    __shared__ float r1[2], r2[2];
    __shared__ float sc[16];
    // --- aggregate_start ---
    int p0 = ptr[g], p1 = ptr[g + 1];
    int cnt = p1 - p0; if (cnt > 16) cnt = 16;
    float q = question[(size_t)g * H + t];
    xin[H + t] = q;
    for (int s = 0; s < cnt; ++s) {
        int node = locals_[p0 + s];
        float v = node_tokens[(size_t)node * H + t] * q;
        for (int off = 32; off; off >>= 1) v += __shfl_down(v, off);
        if ((t & 63) == 0) r1[t >> 6] = v;
        __syncthreads();
        if (t == 0) sc[s] = (r1[0] + r1[1]) * 0.08838834764831845f;
        __syncthreads();
    }
    float m = -1e30f;
    for (int s = 0; s < cnt; ++s) m = fmaxf(m, sc[s]);
    float den = 0.f;
    for (int s = 0; s < cnt; ++s) den += expf(sc[s] - m);
    float acc0 = 0.f;
    for (int s = 0; s < cnt; ++s) {
        float a = expf(sc[s] - m) / den;
        acc0 += a * node_tokens[(size_t)locals_[p0 + s] * H + t];
    }
    xin[t] = acc0;
    __syncthreads();
    // --- ctx MLP ---
    float a1 = cb1[t];
    for (int k = 0; k < 2 * H; ++k) a1 += xin[k] * cw1[k * H + t];
    buf[t] = gelu_exact(a1);
    __syncthreads();
    float ctx = cb2[t];
    for (int k = 0; k < H; ++k) ctx += buf[k] * cw2[k * H + t];
    // --- LN + z head ---
    float s1 = ctx, s2 = ctx * ctx;
    for (int off = 32; off; off >>= 1) { s1 += __shfl_down(s1, off); s2 += __shfl_down(s2, off); }
    if ((t & 63) == 0) { r1[t >> 6] = s1; r2[t >> 6] = s2; }
    __syncthreads();
    float mean = (r1[0] + r1[1]) * (1.f / H);
    float var  = (r2[0] + r2[1]) * (1.f / H) - mean * mean;
    float xn = (ctx - mean) * rsqrtf(var + EPS_LN) * ln1g[t] + ln1b[t];
    __syncthreads();
    buf[t] = xn;
    __syncthreads();
    float a2 = zb1[t];
    for (int k = 0; k < H; ++k) a2 += buf[k] * zw1[k * H + t];
    float p = gelu_exact(a2) * zw2[t];
    for (int off = 32; off; off >>= 1) p += __shfl_down(p, off);
    if ((t & 63) == 0) r1[t >> 6] = p;
    __syncthreads();
    if (t == 0) out[(size_t)g * 3 + 0] = r1[0] + r1[1] + zb2[0];
}

// ---- K4: edge MLP via MFMA, double-buffered LDS B, one barrier per chunk ----
// 256 threads = 4 waves, each wave owns 32 edges (two 16-row A halves share
// every B fragment). B fed by ds_read_b128 (12 cyc, conflict-free — r0's
// proven path; r3 showed global B puts ~200cyc L2 latency per MFMA pair on
// the critical path). Staging is register-split (T14): next chunk's global
// loads issue at the TOP of the iteration, the ds_write lands after the
// MFMA block, ONE __syncthreads per chunk (r0 had two + full drain right
// after the staging loads). 12 barriers per 128 edges vs r0's 24 per 64.
// Lessons pinned in code: 1024-thread blocks => allocator pins 64 VGPR and
// spills ~0.5 GB (r1/r2); bare __launch_bounds__(256) is the good regime.
__global__ __launch_bounds__(256) void k_edges(
    const float* __restrict__ node_tokens, const float* __restrict__ question,
    const float* __restrict__ edge_tokens, const int* __restrict__ edge_batch,
    const int* __restrict__ edge_index,
    const unsigned short* __restrict__ bwbf, const float* __restrict__ colsum,
    const float* __restrict__ bb1p, const float* __restrict__ bw2,
    const float* __restrict__ bb2, float* __restrict__ logits,
    float* __restrict__ sumexp)
{
    __shared__ unsigned short bstage[2][4096];   // 2 x 8 KB double buffer
    int t = threadIdx.x, lane = t & 63, w = t >> 6;
    int quad = lane >> 4, n16 = lane & 15;
    const int* tgt_idx = edge_index + NEDGES;

    int e0w = blockIdx.x * 128 + w * 32;      // this wave's 32 edges
    int ea = e0w + n16;       int eca = ea < NEDGES ? ea : NEDGES - 1;
    int eb = e0w + 16 + n16;  int ecb = eb < NEDGES ? eb : NEDGES - 1;
    int qra = edge_batch[eca], qrb = edge_batch[ecb];
    int tra = tgt_idx[eca],    trb = tgt_idx[ecb];
    const float4* epa = (const float4*)(edge_tokens + (size_t)eca * H);
    const float4* qpa = (const float4*)(question + (size_t)qra * H);
    const float4* npa = (const float4*)(node_tokens + (size_t)tra * H);
    const float4* epb = (const float4*)(edge_tokens + (size_t)ecb * H);
    const float4* qpb = (const float4*)(question + (size_t)qrb * H);
    const float4* npb = (const float4*)(node_tokens + (size_t)trb * H);

    // prologue: stage chunk 0 into buffer 0
    {
        const uint4* src = (const uint4*)bwbf;
        uint4 p0 = src[t], p1 = src[t + 256];
        uint4* dst = (uint4*)bstage[0];
        dst[t] = p0; dst[t + 256] = p1;
    }
    __syncthreads();

    float s1a = 0.f, s2a = 0.f, s1b = 0.f, s2b = 0.f;
    f32x4 acc0[8], acc1[8];
    #pragma unroll
    for (int i = 0; i < 8; ++i) { acc0[i] = (f32x4){0,0,0,0}; acc1[i] = (f32x4){0,0,0,0}; }

    #pragma unroll
    for (int s = 0; s < 12; ++s) {
        int cur = s & 1;
        // (1) issue next chunk's global loads FIRST (latency hides under MFMA)
        uint4 p0, p1;
        if (s < 11) {
            const uint4* src = (const uint4*)(bwbf + (s + 1) * 4096);
            p0 = src[t]; p1 = src[t + 256];
        }
        // (2) A gather for this chunk + LN stats + bf16 fragments
        int c0 = s * 8 + quad * 2;            // float4 index 0..95 of the 3H row
        int cc = c0 - ((s < 4) ? 0 : (s < 8) ? 32 : 64);
        const float4* basea = (s < 4) ? epa : (s < 8) ? qpa : npa;
        const float4* baseb = (s < 4) ? epb : (s < 8) ? qpb : npb;
        float4 v0 = basea[cc], v1 = basea[cc + 1];
        float4 u0 = baseb[cc], u1 = baseb[cc + 1];
        s1a += v0.x + v0.y + v0.z + v0.w + v1.x + v1.y + v1.z + v1.w;
        s2a += v0.x*v0.x + v0.y*v0.y + v0.z*v0.z + v0.w*v0.w
             + v1.x*v1.x + v1.y*v1.y + v1.z*v1.z + v1.w*v1.w;
        s1b += u0.x + u0.y + u0.z + u0.w + u1.x + u1.y + u1.z + u1.w;
        s2b += u0.x*u0.x + u0.y*u0.y + u0.z*u0.z + u0.w*u0.w
             + u1.x*u1.x + u1.y*u1.y + u1.z*u1.z + u1.w*u1.w;
        short8 fa, fb;
        fa[0] = (short)f2bf(v0.x); fa[1] = (short)f2bf(v0.y);
        fa[2] = (short)f2bf(v0.z); fa[3] = (short)f2bf(v0.w);
        fa[4] = (short)f2bf(v1.x); fa[5] = (short)f2bf(v1.y);
        fa[6] = (short)f2bf(v1.z); fa[7] = (short)f2bf(v1.w);
        fb[0] = (short)f2bf(u0.x); fb[1] = (short)f2bf(u0.y);
        fb[2] = (short)f2bf(u0.z); fb[3] = (short)f2bf(u0.w);
        fb[4] = (short)f2bf(u1.x); fb[5] = (short)f2bf(u1.y);
        fb[6] = (short)f2bf(u1.z); fb[7] = (short)f2bf(u1.w);
        // (3) MFMAs on the CURRENT buffer (conflict-free ds_read_b128)
        #pragma unroll
        for (int t8 = 0; t8 < 8; ++t8) {
            short8 b = *(const short8*)&bstage[cur][(t8 * 64 + lane) * 8];
            acc0[t8] = __builtin_amdgcn_mfma_f32_16x16x32_bf16(fa, b, acc0[t8], 0, 0, 0);
            acc1[t8] = __builtin_amdgcn_mfma_f32_16x16x32_bf16(fb, b, acc1[t8], 0, 0, 0);
        }
        // (4) write the prefetched chunk into the OTHER buffer, one barrier
        if (s < 11) {
            uint4* dst = (uint4*)bstage[cur ^ 1];
            dst[t] = p0; dst[t + 256] = p1;
            __syncthreads();
        }
    }

    // full-row LN stats: reduce across the 4 quads sharing each edge row
    s1a += __shfl_xor(s1a, 16); s1a += __shfl_xor(s1a, 32);
    s2a += __shfl_xor(s2a, 16); s2a += __shfl_xor(s2a, 32);
    s1b += __shfl_xor(s1b, 16); s1b += __shfl_xor(s1b, 32);
    s2b += __shfl_xor(s2b, 16); s2b += __shfl_xor(s2b, 32);
    float mua  = s1a * (1.f / 384.f);
    float inva = rsqrtf(s2a * (1.f / 384.f) - mua * mua + EPS_LN);
    float mub  = s1b * (1.f / 384.f);
    float invb = rsqrtf(s2b * (1.f / 384.f) - mub * mub + EPS_LN);
    float bb2v = bb2[0];

    // epilogue per half: y = (acc - mu*colsum)*inv + bb1p ; logit = sum gelu(y)*bw2 + bb2
    #pragma unroll
    for (int h = 0; h < 2; ++h) {
        float muh  = h ? mub : mua;
        float invh = h ? invb : inva;
        #pragma unroll
        for (int r = 0; r < 4; ++r) {
            float mu_r  = __shfl(muh,  quad * 4 + r);
            float inv_r = __shfl(invh, quad * 4 + r);
            float ssum = 0.f;
            #pragma unroll
            for (int t8 = 0; t8 < 8; ++t8) {
                int n = t8 * 16 + n16;
                float a = h ? acc1[t8][r] : acc0[t8][r];
                float y = (a - mu_r * colsum[n]) * inv_r + bb1p[n];
                ssum += gelu_exact(y) * bw2[n];
            }
            ssum += __shfl_xor(ssum, 1);
            ssum += __shfl_xor(ssum, 2);
            ssum += __shfl_xor(ssum, 4);
            ssum += __shfl_xor(ssum, 8);
            if (n16 == 0) {
                int ei = e0w + h * 16 + quad * 4 + r;
                if (ei < NEDGES) {
                    float lg = ssum + bb2v;
                    logits[ei] = lg;
                    // logits are O(1): exp-sum without max-shift is safe
                    atomicAdd(&sumexp[tgt_idx[ei]], expf(lg));
                }
            }
        }
    }
}

// ---- K6: masked per-graph sum of log-probs (LDS slot aggregation) -----------
__global__ __launch_bounds__(256) void k_logpb(
    const float* __restrict__ logits,
    const int* __restrict__ edge_index,
    const int* __restrict__ edge_batch,
    const void* __restrict__ mask,
    const int* __restrict__ flag,
    const float* __restrict__ sumexp,
    float* __restrict__ logpb, int* __restrict__ selcnt)
{
    __shared__ float lacc[8];
    __shared__ int lcnt[8];
    __shared__ int g0s, big;
    int t = threadIdx.x;
    int e0 = blockIdx.x * 256;
    if (t == 0) {
        int ga = edge_batch[e0 < NEDGES ? e0 : NEDGES - 1];
        int el = e0 + 255; if (el >= NEDGES) el = NEDGES - 1;
        int gb = edge_batch[el];
        g0s = ga; big = (gb - ga > 7);
    }
    if (t < 8) { lacc[t] = 0.f; lcnt[t] = 0; }
    __syncthreads();
    int e = e0 + t;
    if (e < NEDGES) {
        int mode = *flag;
        bool sel;
        if (mode & 2)      sel = ((const float*)mask)[e] != 0.f;
        else if (mode & 1) sel = ((const unsigned char*)mask)[e] != 0;
        else               sel = ((const int*)mask)[e] != 0;
        if (sel) {
            int tg = edge_index[NEDGES + e];
            float lp = logits[e] - logf(sumexp[tg]);
            int g = edge_batch[e];
            if (!big) {
                atomicAdd(&lacc[g - g0s], lp);
                atomicAdd(&lcnt[g - g0s], 1);
            } else {
                atomicAdd(&logpb[g], lp);
                atomicAdd(&selcnt[g], 1);
            }
        }
    }
    __syncthreads();
    if (t < 8 && !big && lcnt[t] > 0) {
        atomicAdd(&logpb[g0s + t], lacc[t]);
        atomicAdd(&selcnt[g0s + t], lcnt[t]);
    }
}

// ---- K7: finalize out[:,1] and out[:,2] -------------------------------------
__global__ __launch_bounds__(1024) void k_final(const float* __restrict__ logpb,
                                                const int* __restrict__ selcnt,
                                                float* __restrict__ out)
{
    int g = threadIdx.x;
    float lpb = logpb[g];
    int has = selcnt[g] > 0;
    float s = has ? -lpb : 0.f;
    int c = has;
    __shared__ float rn[16];
    __shared__ int rh[16];
    __shared__ float pbnll_s;
    for (int off = 32; off; off >>= 1) { s += __shfl_down(s, off); c += __shfl_down(c, off); }
    if ((g & 63) == 0) { rn[g >> 6] = s; rh[g >> 6] = c; }
    __syncthreads();
    if (g == 0) {
        float ts = 0.f; int tc = 0;
        for (int i = 0; i < 16; ++i) { ts += rn[i]; tc += rh[i]; }
        pbnll_s = ts / (float)(tc > 0 ? tc : 1);
    }
    __syncthreads();
    out[(size_t)g * 3 + 1] = lpb;
    out[(size_t)g * 3 + 2] = pbnll_s;
}

extern "C" void kernel_launch(void* const* d_in, const int* in_sizes, int n_in,
                              void* d_out, int out_size, void* d_ws, size_t ws_size,
                              hipStream_t stream) {
    const float* node_tokens = (const float*)d_in[0];
    const float* question    = (const float*)d_in[1];
    const float* edge_tokens = (const float*)d_in[2];
    const int*   locals_     = (const int*)d_in[3];
    const int*   ptr         = (const int*)d_in[4];
    const int*   edge_batch  = (const int*)d_in[5];
    const void*  mask        = d_in[6];
    const int*   edge_index  = (const int*)d_in[7];
    const float* ln1g = (const float*)d_in[8];
    const float* ln1b = (const float*)d_in[9];
    const float* zw1  = (const float*)d_in[10];
    const float* zb1  = (const float*)d_in[11];
    const float* zw2  = (const float*)d_in[12];
    const float* zb2  = (const float*)d_in[13];
    const float* cw1  = (const float*)d_in[14];
    const float* cb1  = (const float*)d_in[15];
    const float* cw2  = (const float*)d_in[16];
    const float* cb2  = (const float*)d_in[17];
    const float* blng = (const float*)d_in[18];
    const float* blnb = (const float*)d_in[19];
    const float* bw1  = (const float*)d_in[20];
    const float* bb1  = (const float*)d_in[21];
    const float* bw2  = (const float*)d_in[22];
    const float* bb2  = (const float*)d_in[23];
    float* out = (float*)d_out;

    // workspace layout (float units)
    float* ws = (float*)d_ws;
    float* sumexp  = ws;                                // 100000 (zeroed)
    float* logpb   = ws + 100000;                       // 1024  (zeroed)
    int*   selcnt  = (int*)(ws + 101024);               // 1024  (zeroed)
    int*   flag    = (int*)(ws + 102048);               // 1     (zeroed)
    float* logits  = ws + 102052;                       // 500000
    float* colsum  = ws + 602052;                       // 128
    float* bb1p    = ws + 602180;                       // 128
    unsigned short* bwbf = (unsigned short*)(ws + 602308); // 49152 bf16 (16B-aligned)

    hipMemsetAsync(d_ws, 0, (size_t)102049 * 4, stream);
    k_prep_all<<<321, 256, 0, stream>>>(bw1, blng, blnb, bb1, bwbf, colsum, bb1p,
                                        (const unsigned*)mask, flag);
    k_graph<<<G_NUM, 128, 0, stream>>>(node_tokens, question, locals_, ptr,
                                       cw1, cb1, cw2, cb2, ln1g, ln1b,
                                       zw1, zb1, zw2, zb2, out);
    k_edges<<<(NEDGES + 127) / 128, 256, 0, stream>>>(node_tokens, question, edge_tokens,
                                                      edge_batch, edge_index, bwbf,
                                                      colsum, bb1p, bw2, bb2,
                                                      logits, sumexp);
    int eb = (NEDGES + 255) / 256;
    k_logpb<<<eb, 256, 0, stream>>>(logits, edge_index, edge_batch, mask, flag,
                                    sumexp, logpb, selcnt);
    k_final<<<1, 1024, 0, stream>>>(logpb, selcnt, out);
}

// Round 5
// 672.048 us; speedup vs baseline: 2.1026x; 1.0380x over previous
//
#include <hip/hip_runtime.h>
#include <math.h>

#define G_NUM 1024
#define H 128
#define NNODES 100000
#define NEDGES 500000
#define EPS_LN 1e-5f

typedef __attribute__((ext_vector_type(8))) short short8;
typedef __attribute__((ext_vector_type(4))) float f32x4;

__device__ __forceinline__ float gelu_exact(float x) {
    return 0.5f * x * (1.0f + erff(x * 0.70710678118654752440f));
}
__device__ __forceinline__ unsigned short f2bf(float x) {
    unsigned u = __float_as_uint(x);
    return (unsigned short)((u + 0x7FFFu + ((u >> 16) & 1u)) >> 16);
}

// ---- K_prep_all: fused {bw1 repack, colsum/bb1p, mask probe} ----------------
// fold=1: W1' = diag(blng)*bw1 (fused-fallback path needs LN folded into W).
// fold=0: raw bw1 repack (split path applies LN in k_pack).
// dst: ((s*8 + t8)*64 + lane)*8 + j ; s=k>>5, quad=(k&31)>>3, j=k&7,
// lane=quad*16+(n&15), t8=n>>4
__global__ __launch_bounds__(256) void k_prep_all(
    const float* __restrict__ bw1, const float* __restrict__ blng,
    const float* __restrict__ blnb, const float* __restrict__ bb1,
    unsigned short* __restrict__ bwbf, float* __restrict__ colsum,
    float* __restrict__ bb1p,
    const unsigned* __restrict__ mw, int* __restrict__ flag, int fold)
{
    __shared__ float rc[4], rb[4];
    int b = blockIdx.x, t = threadIdx.x;
    if (b < 192) {
        int e = b * 256 + t;          // 192*256 == 384*128 exactly
        int k = e >> 7, n = e & 127;
        int s = k >> 5, krel = k & 31;
        int quad = krel >> 3, j = krel & 7;
        int lane = quad * 16 + (n & 15);
        int t8 = n >> 4;
        float m = fold ? blng[k] : 1.0f;
        bwbf[((s * 8 + t8) * 64 + lane) * 8 + j] = f2bf(bw1[e] * m);
    } else if (b < 320) {
        int n = b - 192;
        float cs = 0.f, bs = 0.f;
        for (int k = t; k < 384; k += 256) {
            float w = bw1[k * H + n];
            cs += blng[k] * w;
            bs += blnb[k] * w;
        }
        for (int off = 32; off; off >>= 1) {
            cs += __shfl_down(cs, off);
            bs += __shfl_down(bs, off);
        }
        if ((t & 63) == 0) { rc[t >> 6] = cs; rb[t >> 6] = bs; }
        __syncthreads();
        if (t == 0) {
            colsum[n] = rc[0] + rc[1] + rc[2] + rc[3];
            bb1p[n]   = bb1[n] + rb[0] + rb[1] + rb[2] + rb[3];
        }
    } else {
        unsigned v = mw[t];
        if (v == 0x3F800000u) atomicOr(flag, 2);
        else if (v > 1u) atomicOr(flag, 1);
    }
}

// ---- K1: fused aggregate_start + context MLP + log_z -> out[:,0] ------------
__global__ __launch_bounds__(128) void k_graph(
    const float* __restrict__ node_tokens, const float* __restrict__ question,
    const int* __restrict__ locals_, const int* __restrict__ ptr,
    const float* __restrict__ cw1, const float* __restrict__ cb1,
    const float* __restrict__ cw2, const float* __restrict__ cb2,
    const float* __restrict__ ln1g, const float* __restrict__ ln1b,
    const float* __restrict__ zw1, const float* __restrict__ zb1,
    const float* __restrict__ zw2, const float* __restrict__ zb2,
    float* __restrict__ out)
{
    int g = blockIdx.x, t = threadIdx.x;
    __shared__ float xin[2 * H];
    __shared__ float buf[H];
    __shared__ float r1[2], r2[2];
    __shared__ float sc[16];
    // --- aggregate_start ---
    int p0 = ptr[g], p1 = ptr[g + 1];
    int cnt = p1 - p0; if (cnt > 16) cnt = 16;
    float q = question[(size_t)g * H + t];
    xin[H + t] = q;
    for (int s = 0; s < cnt; ++s) {
        int node = locals_[p0 + s];
        float v = node_tokens[(size_t)node * H + t] * q;
        for (int off = 32; off; off >>= 1) v += __shfl_down(v, off);
        if ((t & 63) == 0) r1[t >> 6] = v;
        __syncthreads();
        if (t == 0) sc[s] = (r1[0] + r1[1]) * 0.08838834764831845f;
        __syncthreads();
    }
    float m = -1e30f;
    for (int s = 0; s < cnt; ++s) m = fmaxf(m, sc[s]);
    float den = 0.f;
    for (int s = 0; s < cnt; ++s) den += expf(sc[s] - m);
    float acc0 = 0.f;
    for (int s = 0; s < cnt; ++s) {
        float a = expf(sc[s] - m) / den;
        acc0 += a * node_tokens[(size_t)locals_[p0 + s] * H + t];
    }
    xin[t] = acc0;
    __syncthreads();
    // --- ctx MLP ---
    float a1 = cb1[t];
    for (int k = 0; k < 2 * H; ++k) a1 += xin[k] * cw1[k * H + t];
    buf[t] = gelu_exact(a1);
    __syncthreads();
    float ctx = cb2[t];
    for (int k = 0; k < H; ++k) ctx += buf[k] * cw2[k * H + t];
    // --- LN + z head ---
    float s1 = ctx, s2 = ctx * ctx;
    for (int off = 32; off; off >>= 1) { s1 += __shfl_down(s1, off); s2 += __shfl_down(s2, off); }
    if ((t & 63) == 0) { r1[t >> 6] = s1; r2[t >> 6] = s2; }
    __syncthreads();
    float mean = (r1[0] + r1[1]) * (1.f / H);
    float var  = (r2[0] + r2[1]) * (1.f / H) - mean * mean;
    float xn = (ctx - mean) * rsqrtf(var + EPS_LN) * ln1g[t] + ln1b[t];
    __syncthreads();
    buf[t] = xn;
    __syncthreads();
    float a2 = zb1[t];
    for (int k = 0; k < H; ++k) a2 += buf[k] * zw1[k * H + t];
    float p = gelu_exact(a2) * zw2[t];
    for (int off = 32; off; off >>= 1) p += __shfl_down(p, off);
    if ((t & 63) == 0) r1[t >> 6] = p;
    __syncthreads();
    if (t == 0) out[(size_t)g * 3 + 0] = r1[0] + r1[1] + zb2[0];
}

// ---- K_pack: gather + LayerNorm (f32) + bf16 convert -> A fragment order ----
// Split-path stage 1. Block = 256 thr handles 16 edges (one A tile). Each lane
// owns the OUTPUT positions (s = 3w+i, lane) = 8 consecutive k's of row n16 ->
// reads exactly two float4, writes one coalesced 16B bf16 frag. ~60 VGPR ->
// 8 waves/SIMD: the gather latency that starved the fused kernel (r0-r4 all
// MLP-limited: hbm_gbps tracked occupancy) is hidden by sheer wave count.
__global__ __launch_bounds__(256) void k_pack(
    const float* __restrict__ node_tokens, const float* __restrict__ question,
    const float* __restrict__ edge_tokens, const int* __restrict__ edge_batch,
    const int* __restrict__ edge_index,
    const float* __restrict__ blng, const float* __restrict__ blnb,
    unsigned short* __restrict__ apk, int e_base)
{
    __shared__ float ssm[4][16], ssq[4][16];
    int t = threadIdx.x, lane = t & 63, w = t >> 6;
    int quad = lane >> 4, n16 = lane & 15;
    int e = e_base + blockIdx.x * 16 + n16;
    int ec = e < NEDGES ? e : NEDGES - 1;
    int qrow = edge_batch[ec];
    int trow = edge_index[NEDGES + ec];
    const float4* ep = (const float4*)(edge_tokens + (size_t)ec * H);
    const float4* qp = (const float4*)(question + (size_t)qrow * H);
    const float4* np = (const float4*)(node_tokens + (size_t)trow * H);

    float4 d0a, d0b, d1a, d1b, d2a, d2b;
    float ps = 0.f, pq = 0.f;
    #pragma unroll
    for (int i = 0; i < 3; ++i) {
        int s = w * 3 + i;
        int c0 = s * 8 + quad * 2;
        int cc = c0 - ((s < 4) ? 0 : (s < 8) ? 32 : 64);
        const float4* base = (s < 4) ? ep : (s < 8) ? qp : np;
        float4 v0 = base[cc], v1 = base[cc + 1];
        if (i == 0) { d0a = v0; d0b = v1; }
        else if (i == 1) { d1a = v0; d1b = v1; }
        else { d2a = v0; d2b = v1; }
        ps += v0.x + v0.y + v0.z + v0.w + v1.x + v1.y + v1.z + v1.w;
        pq += v0.x*v0.x + v0.y*v0.y + v0.z*v0.z + v0.w*v0.w
            + v1.x*v1.x + v1.y*v1.y + v1.z*v1.z + v1.w*v1.w;
    }
    // reduce across the 4 quads of this wave (same row n16)
    ps += __shfl_xor(ps, 16); ps += __shfl_xor(ps, 32);
    pq += __shfl_xor(pq, 16); pq += __shfl_xor(pq, 32);
    if (quad == 0) { ssm[w][n16] = ps; ssq[w][n16] = pq; }
    __syncthreads();
    float S = ssm[0][n16] + ssm[1][n16] + ssm[2][n16] + ssm[3][n16];
    float Q = ssq[0][n16] + ssq[1][n16] + ssq[2][n16] + ssq[3][n16];
    float mu  = S * (1.f / 384.f);
    float inv = rsqrtf(Q * (1.f / 384.f) - mu * mu + EPS_LN);

    #pragma unroll
    for (int i = 0; i < 3; ++i) {
        int s = w * 3 + i;
        int k0 = s * 32 + quad * 8;
        float4 g0 = *(const float4*)(blng + k0), g1 = *(const float4*)(blng + k0 + 4);
        float4 b0 = *(const float4*)(blnb + k0), b1 = *(const float4*)(blnb + k0 + 4);
        float4 va = (i == 0) ? d0a : (i == 1) ? d1a : d2a;
        float4 vb = (i == 0) ? d0b : (i == 1) ? d1b : d2b;
        short8 f;
        f[0] = (short)f2bf((va.x - mu) * inv * g0.x + b0.x);
        f[1] = (short)f2bf((va.y - mu) * inv * g0.y + b0.y);
        f[2] = (short)f2bf((va.z - mu) * inv * g0.z + b0.z);
        f[3] = (short)f2bf((va.w - mu) * inv * g0.w + b0.w);
        f[4] = (short)f2bf((vb.x - mu) * inv * g1.x + b1.x);
        f[5] = (short)f2bf((vb.y - mu) * inv * g1.y + b1.y);
        f[6] = (short)f2bf((vb.z - mu) * inv * g1.z + b1.z);
        f[7] = (short)f2bf((vb.w - mu) * inv * g1.w + b1.w);
        *(short8*)&apk[(((size_t)blockIdx.x * 12 + s) * 64 + lane) * 8] = f;
    }
}

// ---- K_gemm: pure streaming GEMM + gelu/bw2 epilogue (split-path stage 2) ---
// 4 waves x 16 edges, A fragments read LINEARLY (16B/lane) from the packed
// chunk (L3-warm), B double-buffered in LDS with one barrier/chunk. No
// gathers, no stats, no f2bf in the loop -> ~80 VGPR, 6 waves/SIMD.
__global__ __launch_bounds__(256) void k_gemm(
    const unsigned short* __restrict__ apk,
    const unsigned short* __restrict__ bwbf,
    const float* __restrict__ bb1, const float* __restrict__ bw2,
    const float* __restrict__ bb2, const int* __restrict__ edge_index,
    float* __restrict__ logits, float* __restrict__ sumexp,
    int e_base, int e_cnt)
{
    __shared__ unsigned short bstage[2][4096];   // 2 x 8 KB double buffer
    int t = threadIdx.x, lane = t & 63, w = t >> 6;
    int quad = lane >> 4, n16 = lane & 15;
    const int* tgt_idx = edge_index + NEDGES;
    int T = blockIdx.x * 4 + w;                  // chunk-local 16-edge tile

    { // prologue: stage chunk 0
        const uint4* src = (const uint4*)bwbf;
        uint4 a = src[t], b = src[t + 256];
        uint4* dst = (uint4*)bstage[0];
        dst[t] = a; dst[t + 256] = b;
    }
    __syncthreads();

    f32x4 acc[8];
    #pragma unroll
    for (int i = 0; i < 8; ++i) acc[i] = (f32x4){0.f, 0.f, 0.f, 0.f};
    const short8* afrag = (const short8*)apk + (size_t)T * 12 * 64;

    #pragma unroll
    for (int s = 0; s < 12; ++s) {
        int cur = s & 1;
        uint4 p0, p1;
        if (s < 11) {                            // prefetch next B chunk
            const uint4* src = (const uint4*)(bwbf + (s + 1) * 4096);
            p0 = src[t]; p1 = src[t + 256];
        }
        short8 fa = afrag[s * 64 + lane];        // linear, coalesced
        #pragma unroll
        for (int t8 = 0; t8 < 8; ++t8) {
            short8 b = *(const short8*)&bstage[cur][(t8 * 64 + lane) * 8];
            acc[t8] = __builtin_amdgcn_mfma_f32_16x16x32_bf16(fa, b, acc[t8], 0, 0, 0);
        }
        if (s < 11) {
            uint4* dst = (uint4*)bstage[cur ^ 1];
            dst[t] = p0; dst[t + 256] = p1;
            __syncthreads();
        }
    }

    float bb2v = bb2[0];
    #pragma unroll
    for (int r = 0; r < 4; ++r) {
        float ssum = 0.f;
        #pragma unroll
        for (int t8 = 0; t8 < 8; ++t8) {
            int n = t8 * 16 + n16;
            float y = acc[t8][r] + bb1[n];       // LN already applied in pack
            ssum += gelu_exact(y) * bw2[n];
        }
        ssum += __shfl_xor(ssum, 1);
        ssum += __shfl_xor(ssum, 2);
        ssum += __shfl_xor(ssum, 4);
        ssum += __shfl_xor(ssum, 8);
        if (n16 == 0) {
            int elocal = T * 16 + quad * 4 + r;
            int ei = e_base + elocal;
            if (elocal < e_cnt && ei < NEDGES) {
                float lg = ssum + bb2v;
                logits[ei] = lg;
                // logits are O(1): exp-sum without max-shift is safe
                atomicAdd(&sumexp[tgt_idx[ei]], expf(lg));
            }
        }
    }
}

// ---- K4 fallback: verbatim r0 fused kernel (used only if ws too small) ------
__global__ __launch_bounds__(256) void k_edges(
    const float* __restrict__ node_tokens, const float* __restrict__ question,
    const float* __restrict__ edge_tokens, const int* __restrict__ edge_batch,
    const int* __restrict__ edge_index,
    const unsigned short* __restrict__ bwbf, const float* __restrict__ colsum,
    const float* __restrict__ bb1p, const float* __restrict__ bw2,
    const float* __restrict__ bb2, float* __restrict__ logits,
    float* __restrict__ sumexp)
{
    __shared__ unsigned short bstage[4096];   // 8 KB
    int t = threadIdx.x, lane = t & 63, w = t >> 6;
    int quad = lane >> 4, n16 = lane & 15;
    int e0 = blockIdx.x * 64;
    int e = e0 + w * 16 + n16;
    int ec = e < NEDGES ? e : NEDGES - 1;
    int qrow = edge_batch[ec];
    int trow = edge_index[NEDGES + ec];
    const float4* ep = (const float4*)(edge_tokens + (size_t)ec * H);
    const float4* qp = (const float4*)(question + (size_t)qrow * H);
    const float4* np_ = (const float4*)(node_tokens + (size_t)trow * H);

    float s1 = 0.f, s2 = 0.f;
    short8 frag[12];
    #pragma unroll
    for (int s = 0; s < 12; ++s) {
        int c0 = s * 8 + quad * 2;
        const float4* base = (s < 4) ? ep : (s < 8) ? qp : np_;
        int cc = c0 - ((s < 4) ? 0 : (s < 8) ? 32 : 64);
        float4 v0 = base[cc], v1 = base[cc + 1];
        s1 += v0.x + v0.y + v0.z + v0.w + v1.x + v1.y + v1.z + v1.w;
        s2 += v0.x*v0.x + v0.y*v0.y + v0.z*v0.z + v0.w*v0.w
            + v1.x*v1.x + v1.y*v1.y + v1.z*v1.z + v1.w*v1.w;
        short8 f;
        f[0] = (short)f2bf(v0.x); f[1] = (short)f2bf(v0.y);
        f[2] = (short)f2bf(v0.z); f[3] = (short)f2bf(v0.w);
        f[4] = (short)f2bf(v1.x); f[5] = (short)f2bf(v1.y);
        f[6] = (short)f2bf(v1.z); f[7] = (short)f2bf(v1.w);
        frag[s] = f;
    }
    s1 += __shfl_xor(s1, 16); s1 += __shfl_xor(s1, 32);
    s2 += __shfl_xor(s2, 16); s2 += __shfl_xor(s2, 32);
    float mu  = s1 * (1.f / 384.f);
    float inv = rsqrtf(s2 * (1.f / 384.f) - mu * mu + EPS_LN);

    f32x4 acc[8];
    #pragma unroll
    for (int q = 0; q < 8; ++q) acc[q] = (f32x4){0.f, 0.f, 0.f, 0.f};

    #pragma unroll
    for (int s = 0; s < 12; ++s) {
        __syncthreads();
        {
            const uint4* src = (const uint4*)(bwbf + s * 4096);
            uint4* dst = (uint4*)bstage;
            dst[t] = src[t];
            dst[t + 256] = src[t + 256];
        }
        __syncthreads();
        #pragma unroll
        for (int t8 = 0; t8 < 8; ++t8) {
            short8 b = *(const short8*)&bstage[(t8 * 64 + lane) * 8];
            acc[t8] = __builtin_amdgcn_mfma_f32_16x16x32_bf16(frag[s], b, acc[t8], 0, 0, 0);
        }
    }

    float csv[8], bbv[8], w2v[8];
    #pragma unroll
    for (int t8 = 0; t8 < 8; ++t8) {
        int n = t8 * 16 + n16;
        csv[t8] = colsum[n]; bbv[t8] = bb1p[n]; w2v[t8] = bw2[n];
    }
    float bb2v = bb2[0];
    #pragma unroll
    for (int r = 0; r < 4; ++r) {
        float mu_r  = __shfl(mu,  quad * 4 + r);
        float inv_r = __shfl(inv, quad * 4 + r);
        float ssum = 0.f;
        #pragma unroll
        for (int t8 = 0; t8 < 8; ++t8) {
            float y = (acc[t8][r] - mu_r * csv[t8]) * inv_r + bbv[t8];
            ssum += gelu_exact(y) * w2v[t8];
        }
        ssum += __shfl_xor(ssum, 1);
        ssum += __shfl_xor(ssum, 2);
        ssum += __shfl_xor(ssum, 4);
        ssum += __shfl_xor(ssum, 8);
        if (n16 == 0) {
            int ei = e0 + w * 16 + quad * 4 + r;
            if (ei < NEDGES) {
                float lg = ssum + bb2v;
                logits[ei] = lg;
                atomicAdd(&sumexp[edge_index[NEDGES + ei]], expf(lg));
            }
        }
    }
}

// ---- K6: masked per-graph sum of log-probs (LDS slot aggregation) -----------
__global__ __launch_bounds__(256) void k_logpb(
    const float* __restrict__ logits,
    const int* __restrict__ edge_index,
    const int* __restrict__ edge_batch,
    const void* __restrict__ mask,
    const int* __restrict__ flag,
    const float* __restrict__ sumexp,
    float* __restrict__ logpb, int* __restrict__ selcnt)
{
    __shared__ float lacc[8];
    __shared__ int lcnt[8];
    __shared__ int g0s, big;
    int t = threadIdx.x;
    int e0 = blockIdx.x * 256;
    if (t == 0) {
        int ga = edge_batch[e0 < NEDGES ? e0 : NEDGES - 1];
        int el = e0 + 255; if (el >= NEDGES) el = NEDGES - 1;
        int gb = edge_batch[el];
        g0s = ga; big = (gb - ga > 7);
    }
    if (t < 8) { lacc[t] = 0.f; lcnt[t] = 0; }
    __syncthreads();
    int e = e0 + t;
    if (e < NEDGES) {
        int mode = *flag;
        bool sel;
        if (mode & 2)      sel = ((const float*)mask)[e] != 0.f;
        else if (mode & 1) sel = ((const unsigned char*)mask)[e] != 0;
        else               sel = ((const int*)mask)[e] != 0;
        if (sel) {
            int tg = edge_index[NEDGES + e];
            float lp = logits[e] - logf(sumexp[tg]);
            int g = edge_batch[e];
            if (!big) {
                atomicAdd(&lacc[g - g0s], lp);
                atomicAdd(&lcnt[g - g0s], 1);
            } else {
                atomicAdd(&logpb[g], lp);
                atomicAdd(&selcnt[g], 1);
            }
        }
    }
    __syncthreads();
    if (t < 8 && !big && lcnt[t] > 0) {
        atomicAdd(&logpb[g0s + t], lacc[t]);
        atomicAdd(&selcnt[g0s + t], lcnt[t]);
    }
}

// ---- K7: finalize out[:,1] and out[:,2] -------------------------------------
__global__ __launch_bounds__(1024) void k_final(const float* __restrict__ logpb,
                                                const int* __restrict__ selcnt,
                                                float* __restrict__ out)
{
    int g = threadIdx.x;
    float lpb = logpb[g];
    int has = selcnt[g] > 0;
    float s = has ? -lpb : 0.f;
    int c = has;
    __shared__ float rn[16];
    __shared__ int rh[16];
    __shared__ float pbnll_s;
    for (int off = 32; off; off >>= 1) { s += __shfl_down(s, off); c += __shfl_down(c, off); }
    if ((g & 63) == 0) { rn[g >> 6] = s; rh[g >> 6] = c; }
    __syncthreads();
    if (g == 0) {
        float ts = 0.f; int tc = 0;
        for (int i = 0; i < 16; ++i) { ts += rn[i]; tc += rh[i]; }
        pbnll_s = ts / (float)(tc > 0 ? tc : 1);
    }
    __syncthreads();
    out[(size_t)g * 3 + 1] = lpb;
    out[(size_t)g * 3 + 2] = pbnll_s;
}

extern "C" void kernel_launch(void* const* d_in, const int* in_sizes, int n_in,
                              void* d_out, int out_size, void* d_ws, size_t ws_size,
                              hipStream_t stream) {
    const float* node_tokens = (const float*)d_in[0];
    const float* question    = (const float*)d_in[1];
    const float* edge_tokens = (const float*)d_in[2];
    const int*   locals_     = (const int*)d_in[3];
    const int*   ptr         = (const int*)d_in[4];
    const int*   edge_batch  = (const int*)d_in[5];
    const void*  mask        = d_in[6];
    const int*   edge_index  = (const int*)d_in[7];
    const float* ln1g = (const float*)d_in[8];
    const float* ln1b = (const float*)d_in[9];
    const float* zw1  = (const float*)d_in[10];
    const float* zb1  = (const float*)d_in[11];
    const float* zw2  = (const float*)d_in[12];
    const float* zb2  = (const float*)d_in[13];
    const float* cw1  = (const float*)d_in[14];
    const float* cb1  = (const float*)d_in[15];
    const float* cw2  = (const float*)d_in[16];
    const float* cb2  = (const float*)d_in[17];
    const float* blng = (const float*)d_in[18];
    const float* blnb = (const float*)d_in[19];
    const float* bw1  = (const float*)d_in[20];
    const float* bb1  = (const float*)d_in[21];
    const float* bw2  = (const float*)d_in[22];
    const float* bb2  = (const float*)d_in[23];
    float* out = (float*)d_out;

    // workspace layout (float units)
    float* ws = (float*)d_ws;
    float* sumexp  = ws;                                // 100000 (zeroed)
    float* logpb   = ws + 100000;                       // 1024  (zeroed)
    int*   selcnt  = (int*)(ws + 101024);               // 1024  (zeroed)
    int*   flag    = (int*)(ws + 102048);               // 1     (zeroed)
    float* logits  = ws + 102052;                       // 500000
    float* colsum  = ws + 602052;                       // 128
    float* bb1p    = ws + 602180;                       // 128
    unsigned short* bwbf = (unsigned short*)(ws + 602308); // 49152 bf16
    const size_t base_floats = 626884;                  // end of fixed layout (16B-aligned)
    unsigned short* apk = (unsigned short*)(ws + base_floats);

    // choose split-chunk size from available workspace (768 B per edge)
    int CH = 0;
    if (ws_size > base_floats * 4) {
        size_t cap = (ws_size - base_floats * 4) / 768;
        if      (cap >= 131072) CH = 131072;
        else if (cap >= 65536)  CH = 65536;
        else if (cap >= 32768)  CH = 32768;
        else if (cap >= 16384)  CH = 16384;
    }

    hipMemsetAsync(d_ws, 0, (size_t)102049 * 4, stream);
    k_prep_all<<<321, 256, 0, stream>>>(bw1, blng, blnb, bb1, bwbf, colsum, bb1p,
                                        (const unsigned*)mask, flag, CH ? 0 : 1);
    k_graph<<<G_NUM, 128, 0, stream>>>(node_tokens, question, locals_, ptr,
                                       cw1, cb1, cw2, cb2, ln1g, ln1b,
                                       zw1, zb1, zw2, zb2, out);
    if (CH) {
        for (int e0 = 0; e0 < NEDGES; e0 += CH) {
            int cnt = NEDGES - e0 < CH ? NEDGES - e0 : CH;
            k_pack<<<(cnt + 15) / 16, 256, 0, stream>>>(node_tokens, question,
                                                        edge_tokens, edge_batch,
                                                        edge_index, blng, blnb,
                                                        apk, e0);
            k_gemm<<<(cnt + 63) / 64, 256, 0, stream>>>(apk, bwbf, bb1, bw2, bb2,
                                                        edge_index, logits, sumexp,
                                                        e0, cnt);
        }
    } else {
        k_edges<<<(NEDGES + 63) / 64, 256, 0, stream>>>(node_tokens, question,
                                                        edge_tokens, edge_batch,
                                                        edge_index, bwbf, colsum,
                                                        bb1p, bw2, bb2,
                                                        logits, sumexp);
    }
    int eb = (NEDGES + 255) / 256;
    k_logpb<<<eb, 256, 0, stream>>>(logits, edge_index, edge_batch, mask, flag,
                                    sumexp, logpb, selcnt);
    k_final<<<1, 1024, 0, stream>>>(logpb, selcnt, out);
}